// Round 1
// baseline (445.258 us; speedup 1.0000x reference)
//
#include <hip/hip_runtime.h>

typedef __attribute__((ext_vector_type(4))) float f32x4;
typedef __attribute__((ext_vector_type(8))) short s16x8;

#define B_   96
#define NQ   35
#define LP   180
#define H_   768
#define D_   128
#define NEGF (-1e30f)

__device__ __forceinline__ unsigned short f2bf(float f) {
    unsigned int u = __float_as_uint(f);
    u += 0x7fffu + ((u >> 16) & 1u);
    return (unsigned short)(u >> 16);
}
__device__ __forceinline__ float bf2f(unsigned short h) {
    return __uint_as_float(((unsigned int)h) << 16);
}

// ---------------- mask dtype detection + canonicalization ----------------
// Scan first 17280 bytes (safe for every candidate layout).
__global__ void mask_detect(const unsigned char* __restrict__ mp, unsigned int* __restrict__ ctrl) {
    int i = blockIdx.x * 256 + threadIdx.x;
    if (i >= B_ * LP) return;
    unsigned char v = mp[i];
    if (v) {
        if ((i & 3) == 1) atomicAdd(&ctrl[0], 1u);  // >0 => 1-byte layout (bool/int8)
        if ((i & 3) == 3) atomicAdd(&ctrl[1], 1u);  // >0 => float32 (0x3f byte of 1.0f)
        if ((i & 7) == 4) atomicAdd(&ctrl[2], 1u);  // >0 => int32 (odd elements' low byte)
    }
}

__global__ void mask_canon(const void* __restrict__ pm, const void* __restrict__ nm,
                           const unsigned int* __restrict__ ctrl, unsigned char* __restrict__ outm) {
    int i = blockIdx.x * 256 + threadIdx.x;
    if (i >= 2 * B_ * LP) return;
    const void* src = (i < B_ * LP) ? pm : nm;
    int j = (i < B_ * LP) ? i : i - B_ * LP;
    unsigned int c1 = ctrl[0], c3 = ctrl[1], c4 = ctrl[2];
    bool bit;
    if (c1 > 0)       bit = ((const unsigned char*)src)[j] != 0;   // bool / int8
    else if (c3 > 0)  bit = ((const float*)src)[j] != 0.0f;        // float32
    else if (c4 > 0)  bit = ((const int*)src)[j] != 0;             // int32
    else              bit = ((const long long*)src)[j] != 0;       // int64
    outm[i] = bit ? 1 : 0;
}

// ---------------- W transpose + hi/lo bf16 split ----------------
// W [768][128] f32 -> Wt_hi/Wt_lo [128][768] bf16 (contiguous in k for B-frag loads)
__global__ void wt_build(const float* __restrict__ W,
                         unsigned short* __restrict__ wthi, unsigned short* __restrict__ wtlo) {
    int o = blockIdx.x * 256 + threadIdx.x;
    if (o >= D_ * H_) return;
    int d = o / H_, k = o - d * H_;
    float v = W[k * D_ + d];
    unsigned short h = f2bf(v);
    wthi[o] = h;
    wtlo[o] = f2bf(v - bf2f(h));
}

// ---------------- projection GEMM: x = h @ W + b (fp32 out, hi/lo bf16 MFMA) ----------------
// One wave computes 32 rows x 128 cols. Row groups: q 105, pos 540, neg 540 (total 1185).
__global__ __launch_bounds__(256) void proj_k(
    const float* __restrict__ qh, const float* __restrict__ ph, const float* __restrict__ nh,
    const unsigned short* __restrict__ wthi, const unsigned short* __restrict__ wtlo,
    const float* __restrict__ bias,
    float* __restrict__ xq, float* __restrict__ xp, float* __restrict__ xn) {
    int wave = threadIdx.x >> 6, lane = threadIdx.x & 63;
    int rg = blockIdx.x * 4 + wave;
    if (rg >= 1185) return;
    const float* src; float* dst; int row0;
    if (rg < 105)      { src = qh; dst = xq; row0 = rg * 32; }
    else if (rg < 645) { src = ph; dst = xp; row0 = (rg - 105) * 32; }
    else               { src = nh; dst = xn; row0 = (rg - 645) * 32; }
    int m = lane & 15, quad = lane >> 4;

    f32x4 acc[2][8];
#pragma unroll
    for (int mt = 0; mt < 2; mt++)
#pragma unroll
        for (int nt = 0; nt < 8; nt++) acc[mt][nt] = (f32x4){0.f, 0.f, 0.f, 0.f};

    const float* a0 = src + (size_t)(row0 + m) * H_ + quad * 8;
    const float* a1 = src + (size_t)(row0 + 16 + m) * H_ + quad * 8;

    for (int ks = 0; ks < 24; ks++) {
        s16x8 ahi[2], alo[2];
#pragma unroll
        for (int mt = 0; mt < 2; mt++) {
            const f32x4* pA = (const f32x4*)((mt == 0 ? a0 : a1) + ks * 32);
            f32x4 v0 = pA[0], v1 = pA[1];
#pragma unroll
            for (int j = 0; j < 4; j++) {
                unsigned short h0 = f2bf(v0[j]);
                ahi[mt][j] = (short)h0; alo[mt][j] = (short)f2bf(v0[j] - bf2f(h0));
                unsigned short h1 = f2bf(v1[j]);
                ahi[mt][4 + j] = (short)h1; alo[mt][4 + j] = (short)f2bf(v1[j] - bf2f(h1));
            }
        }
#pragma unroll
        for (int nt = 0; nt < 8; nt++) {
            size_t wo = (size_t)(nt * 16 + m) * H_ + ks * 32 + quad * 8;
            s16x8 bhi = *(const s16x8*)(wthi + wo);
            s16x8 blo = *(const s16x8*)(wtlo + wo);
#pragma unroll
            for (int mt = 0; mt < 2; mt++) {
                acc[mt][nt] = __builtin_amdgcn_mfma_f32_16x16x32_bf16(ahi[mt], bhi, acc[mt][nt], 0, 0, 0);
                acc[mt][nt] = __builtin_amdgcn_mfma_f32_16x16x32_bf16(alo[mt], bhi, acc[mt][nt], 0, 0, 0);
                acc[mt][nt] = __builtin_amdgcn_mfma_f32_16x16x32_bf16(ahi[mt], blo, acc[mt][nt], 0, 0, 0);
            }
        }
    }
    // epilogue: + bias, store fp32.  D layout: col=lane&15, row=quad*4+r
#pragma unroll
    for (int nt = 0; nt < 8; nt++) {
        int col = nt * 16 + m;
        float bv = bias[col];
#pragma unroll
        for (int mt = 0; mt < 2; mt++)
#pragma unroll
            for (int r = 0; r < 4; r++) {
                int row = row0 + mt * 16 + quad * 4 + r;
                dst[(size_t)row * D_ + col] = acc[mt][nt][r] + bv;
            }
    }
}

// ---------------- normalization over the SEQUENCE axis ----------------
__global__ __launch_bounds__(128) void normalize_k(
    const float* __restrict__ xq, const float* __restrict__ xp, const float* __restrict__ xn,
    unsigned short* __restrict__ qn, unsigned short* __restrict__ pn, unsigned short* __restrict__ nn) {
    int b = blockIdx.x, d = threadIdx.x;
    const float* x; unsigned short* o; int L;
    if (b < B_)          { x = xq + (size_t)b * NQ * D_;          o = qn + (size_t)b * NQ * D_;          L = NQ; }
    else if (b < 2 * B_) { x = xp + (size_t)(b - B_) * LP * D_;   o = pn + (size_t)(b - B_) * LP * D_;   L = LP; }
    else                 { x = xn + (size_t)(b - 2 * B_) * LP * D_; o = nn + (size_t)(b - 2 * B_) * LP * D_; L = LP; }
    float s = 0.f;
    for (int l = 0; l < L; l++) { float v = x[l * D_ + d]; s += v * v; }
    float inv = 1.0f / fmaxf(sqrtf(s), 1e-12f);
    for (int l = 0; l < L; l++) o[l * D_ + d] = f2bf(x[l * D_ + d] * inv);
}

// ---------------- late interaction: one wave per (qb, pb, side) ----------------
__global__ __launch_bounds__(256) void interact_k(
    const unsigned short* __restrict__ qn, const unsigned short* __restrict__ pn,
    const unsigned short* __restrict__ nn, const unsigned char* __restrict__ maskc,
    float* __restrict__ out) {
    int wave = threadIdx.x >> 6, lane = threadIdx.x & 63;
    int pidx = blockIdx.x * 4 + wave;             // < 18432
    int side = pidx / (B_ * B_);
    int rem = pidx - side * (B_ * B_);
    int qb = rem / B_, pb = rem - (rem / B_) * B_;
    const unsigned short* p = (side ? nn : pn) + (size_t)pb * LP * D_;
    const unsigned char* mk = maskc + side * (B_ * LP) + pb * LP;
    int m = lane & 15, quad = lane >> 4;

    // preload q fragments: A[m][k], m=lane&15, k=quad*8+j
    s16x8 a[3][4];
    const unsigned short* qbase = qn + (size_t)qb * NQ * D_;
#pragma unroll
    for (int mt = 0; mt < 3; mt++) {
        int row = mt * 16 + m;
        if (row < NQ) {
#pragma unroll
            for (int ks = 0; ks < 4; ks++)
                a[mt][ks] = *(const s16x8*)(qbase + (size_t)row * D_ + ks * 32 + quad * 8);
        } else {
#pragma unroll
            for (int ks = 0; ks < 4; ks++) a[mt][ks] = (s16x8){0, 0, 0, 0, 0, 0, 0, 0};
        }
    }

    float rmax[3][4];
#pragma unroll
    for (int mt = 0; mt < 3; mt++)
#pragma unroll
        for (int r = 0; r < 4; r++) rmax[mt][r] = NEGF;

    for (int nt = 0; nt < 12; nt++) {
        int l = nt * 16 + m;
        int lc = l < LP ? l : LP - 1;
        bool valid = (l < LP) && (mk[lc] != 0);
        s16x8 bfr[4];
#pragma unroll
        for (int ks = 0; ks < 4; ks++)
            bfr[ks] = *(const s16x8*)(p + (size_t)lc * D_ + ks * 32 + quad * 8);
#pragma unroll
        for (int mt = 0; mt < 3; mt++) {
            f32x4 acc = (f32x4){0.f, 0.f, 0.f, 0.f};
#pragma unroll
            for (int ks = 0; ks < 4; ks++)
                acc = __builtin_amdgcn_mfma_f32_16x16x32_bf16(a[mt][ks], bfr[ks], acc, 0, 0, 0);
#pragma unroll
            for (int r = 0; r < 4; r++) {
                float v = valid ? acc[r] : NEGF;
                rmax[mt][r] = fmaxf(rmax[mt][r], v);
            }
        }
    }

    // max over columns: reduce across the 16 lanes sharing the same quad
#pragma unroll
    for (int mt = 0; mt < 3; mt++)
#pragma unroll
        for (int r = 0; r < 4; r++) {
            float v = rmax[mt][r];
            v = fmaxf(v, __shfl_xor(v, 1));
            v = fmaxf(v, __shfl_xor(v, 2));
            v = fmaxf(v, __shfl_xor(v, 4));
            v = fmaxf(v, __shfl_xor(v, 8));
            rmax[mt][r] = v;
        }
    // sum over valid rows (rows of this quad), then sum across quads
    float s = 0.f;
#pragma unroll
    for (int mt = 0; mt < 3; mt++)
#pragma unroll
        for (int r = 0; r < 4; r++) {
            int row = mt * 16 + quad * 4 + r;
            if (row < NQ) s += rmax[mt][r];
        }
    s += __shfl_xor(s, 16);
    s += __shfl_xor(s, 32);
    if (lane == 0) out[(size_t)qb * (2 * B_) + side * B_ + pb] = s;
}

// ---------------- launch ----------------
extern "C" void kernel_launch(void* const* d_in, const int* in_sizes, int n_in,
                              void* d_out, int out_size, void* d_ws, size_t ws_size,
                              hipStream_t stream) {
    const float* qh   = (const float*)d_in[0];
    const float* ph   = (const float*)d_in[1];
    const float* nh   = (const float*)d_in[2];
    const float* W    = (const float*)d_in[3];
    const float* bias = (const float*)d_in[4];
    const void* pmask = d_in[5];
    const void* nmask = d_in[6];
    float* out = (float*)d_out;
    char* ws = (char*)d_ws;

    constexpr size_t CTRL_OFF  = 0;
    constexpr size_t WTHI_OFF  = 256;
    constexpr size_t WTLO_OFF  = WTHI_OFF + (size_t)D_ * H_ * 2;             // 196864
    constexpr size_t MASKC_OFF = WTLO_OFF + (size_t)D_ * H_ * 2;             // 393472
    constexpr size_t XQ_OFF    = MASKC_OFF + 2 * B_ * LP;                    // 428032 (256-aligned)
    constexpr size_t XP_OFF    = XQ_OFF + (size_t)B_ * NQ * D_ * 4;
    constexpr size_t XN_OFF    = XP_OFF + (size_t)B_ * LP * D_ * 4;
    constexpr size_t QN_OFF    = XN_OFF + (size_t)B_ * LP * D_ * 4;
    constexpr size_t PN_OFF    = QN_OFF + (size_t)B_ * NQ * D_ * 2;
    constexpr size_t NN_OFF    = PN_OFF + (size_t)B_ * LP * D_ * 2;

    unsigned int* ctrl   = (unsigned int*)(ws + CTRL_OFF);
    unsigned short* wthi = (unsigned short*)(ws + WTHI_OFF);
    unsigned short* wtlo = (unsigned short*)(ws + WTLO_OFF);
    unsigned char* maskc = (unsigned char*)(ws + MASKC_OFF);
    float* xq = (float*)(ws + XQ_OFF);
    float* xp = (float*)(ws + XP_OFF);
    float* xn = (float*)(ws + XN_OFF);
    unsigned short* qnb = (unsigned short*)(ws + QN_OFF);
    unsigned short* pnb = (unsigned short*)(ws + PN_OFF);
    unsigned short* nnb = (unsigned short*)(ws + NN_OFF);

    hipMemsetAsync(ws + CTRL_OFF, 0, 64, stream);
    mask_detect<<<(B_ * LP + 255) / 256, 256, 0, stream>>>((const unsigned char*)pmask, ctrl);
    mask_canon<<<(2 * B_ * LP + 255) / 256, 256, 0, stream>>>(pmask, nmask, ctrl, maskc);
    wt_build<<<(D_ * H_) / 256, 256, 0, stream>>>(W, wthi, wtlo);
    proj_k<<<297, 256, 0, stream>>>(qh, ph, nh, wthi, wtlo, bias, xq, xp, xn);
    normalize_k<<<3 * B_, 128, 0, stream>>>(xq, xp, xn, qnb, pnb, nnb);
    interact_k<<<(2 * B_ * B_) / 4, 256, 0, stream>>>(qnb, pnb, nnb, maskc, out);
}

// Round 2
// 277.935 us; speedup vs baseline: 1.6020x; 1.6020x over previous
//
#include <hip/hip_runtime.h>

typedef __attribute__((ext_vector_type(4))) float f32x4;
typedef __attribute__((ext_vector_type(8))) short s16x8;

#define B_   96
#define NQ   35
#define LP   180
#define H_   768
#define D_   128
#define NEGF (-1e30f)

// row layout of the projected matrix x (37920 rows x 128):
//   q rows   [0, 3360):      row = b*35 + l
//   pos rows [3360, 20640):  row = 3360  + b*180 + l
//   neg rows [20640, 37920): row = 20640 + b*180 + l
#define NROWS 37920
#define QROWS 3360
#define PROWS 17280

__device__ __forceinline__ unsigned short f2bf(float f) {
    unsigned int u = __float_as_uint(f);
    u += 0x7fffu + ((u >> 16) & 1u);
    return (unsigned short)(u >> 16);
}
__device__ __forceinline__ float bf2f(unsigned short h) {
    return __uint_as_float(((unsigned int)h) << 16);
}

// ---------------- mask dtype detection + canonicalization ----------------
__global__ void mask_detect(const unsigned char* __restrict__ mp, unsigned int* __restrict__ ctrl) {
    int i = blockIdx.x * 256 + threadIdx.x;
    if (i >= B_ * LP) return;
    unsigned char v = mp[i];
    if (v) {
        if ((i & 3) == 1) atomicAdd(&ctrl[0], 1u);  // 1-byte layout (bool/int8)
        if ((i & 3) == 3) atomicAdd(&ctrl[1], 1u);  // float32
        if ((i & 7) == 4) atomicAdd(&ctrl[2], 1u);  // int32
    }
}

__global__ void mask_canon(const void* __restrict__ pm, const void* __restrict__ nm,
                           const unsigned int* __restrict__ ctrl, unsigned char* __restrict__ outm) {
    int i = blockIdx.x * 256 + threadIdx.x;
    if (i >= 2 * B_ * LP) return;
    const void* src = (i < B_ * LP) ? pm : nm;
    int j = (i < B_ * LP) ? i : i - B_ * LP;
    unsigned int c1 = ctrl[0], c3 = ctrl[1], c4 = ctrl[2];
    bool bit;
    if (c1 > 0)       bit = ((const unsigned char*)src)[j] != 0;
    else if (c3 > 0)  bit = ((const float*)src)[j] != 0.0f;
    else if (c4 > 0)  bit = ((const int*)src)[j] != 0;
    else              bit = ((const long long*)src)[j] != 0;
    outm[i] = bit ? 1 : 0;
}

// ---------------- W -> fragment-ordered bf16 (hi only) ----------------
// wthi_f[((nt*24 + ks)*64 + lane)*8 + j] = bf16(W[(ks*32 + (lane>>4)*8 + j)*128 + nt*16 + (lane&15)])
__global__ void wt_build(const float* __restrict__ W, unsigned short* __restrict__ wthi) {
    int tid = blockIdx.x * 256 + threadIdx.x;            // 12288 total
    int nt = tid / (24 * 64);
    int r = tid - nt * 24 * 64;
    int ks = r / 64, lane = r - ks * 64;
    int m = lane & 15, quad = lane >> 4;
    unsigned short* o = wthi + (size_t)tid * 8;
#pragma unroll
    for (int j = 0; j < 8; j++) {
        int k = ks * 32 + quad * 8 + j;
        o[j] = f2bf(W[(size_t)k * D_ + nt * 16 + m]);
    }
}

// ---------------- projection GEMM, K-split x2, fragment-ordered B ----------------
// wave w: kh = w/1185 (K-half), rg = w%1185 (32-row group). 2-term hi/lo on A, hi-only B.
__global__ __launch_bounds__(256) void proj_k(
    const float* __restrict__ qh, const float* __restrict__ ph, const float* __restrict__ nh,
    const unsigned short* __restrict__ wthi,
    float* __restrict__ x0, float* __restrict__ x1) {
    int wave = threadIdx.x >> 6, lane = threadIdx.x & 63;
    int w = blockIdx.x * 4 + wave;
    if (w >= 2370) return;
    int kh = w / 1185, rg = w - kh * 1185;
    const float* src; size_t growbase; int row0l;
    if (rg < 105)      { src = qh; row0l = rg * 32;        growbase = row0l; }
    else if (rg < 645) { src = ph; row0l = (rg - 105) * 32; growbase = QROWS + row0l; }
    else               { src = nh; row0l = (rg - 645) * 32; growbase = QROWS + PROWS + row0l; }
    float* dst = kh ? x1 : x0;
    int m = lane & 15, quad = lane >> 4;
    const float* a0 = src + (size_t)(row0l + m) * H_ + quad * 8;
    const float* a1 = a0 + (size_t)16 * H_;

    f32x4 acc[2][8];
#pragma unroll
    for (int mt = 0; mt < 2; mt++)
#pragma unroll
        for (int nt = 0; nt < 8; nt++) acc[mt][nt] = (f32x4){0.f, 0.f, 0.f, 0.f};

    for (int kl = 0; kl < 12; kl++) {
        int ksg = kh * 12 + kl;
        s16x8 ahi[2], alo[2];
#pragma unroll
        for (int mt = 0; mt < 2; mt++) {
            const f32x4* pA = (const f32x4*)((mt == 0 ? a0 : a1) + ksg * 32);
            f32x4 v0 = pA[0], v1 = pA[1];
#pragma unroll
            for (int j = 0; j < 4; j++) {
                unsigned short h0 = f2bf(v0[j]);
                ahi[mt][j] = (short)h0; alo[mt][j] = (short)f2bf(v0[j] - bf2f(h0));
                unsigned short h1 = f2bf(v1[j]);
                ahi[mt][4 + j] = (short)h1; alo[mt][4 + j] = (short)f2bf(v1[j] - bf2f(h1));
            }
        }
        s16x8 bh[8];
#pragma unroll
        for (int nt = 0; nt < 8; nt++)
            bh[nt] = *(const s16x8*)(wthi + ((size_t)(nt * 24 + ksg) * 64 + lane) * 8);
#pragma unroll
        for (int nt = 0; nt < 8; nt++)
#pragma unroll
            for (int mt = 0; mt < 2; mt++) {
                acc[mt][nt] = __builtin_amdgcn_mfma_f32_16x16x32_bf16(ahi[mt], bh[nt], acc[mt][nt], 0, 0, 0);
                acc[mt][nt] = __builtin_amdgcn_mfma_f32_16x16x32_bf16(alo[mt], bh[nt], acc[mt][nt], 0, 0, 0);
            }
    }
    // D layout: col = lane&15, row = quad*4 + r (+ mt*16)
#pragma unroll
    for (int nt = 0; nt < 8; nt++)
#pragma unroll
        for (int mt = 0; mt < 2; mt++)
#pragma unroll
            for (int r = 0; r < 4; r++) {
                size_t grow = growbase + mt * 16 + quad * 4 + r;
                dst[grow * D_ + nt * 16 + m] = acc[mt][nt][r];
            }
}

// ---------------- norm over sequence axis: inv[bk*128+d] ----------------
// bk: 0..95 q, 96..191 pos, 192..287 neg
__global__ __launch_bounds__(256) void norm_inv_k(
    const float* __restrict__ x0, const float* __restrict__ x1, const float* __restrict__ bias,
    float* __restrict__ inv) {
    __shared__ float red[256];
    int bk = blockIdx.x, t = threadIdx.x;
    int d = t & 127, half = t >> 7;
    int L; size_t rowbase;
    if (bk < 96)       { L = NQ; rowbase = (size_t)bk * NQ; }
    else if (bk < 192) { L = LP; rowbase = QROWS + (size_t)(bk - 96) * LP; }
    else               { L = LP; rowbase = QROWS + PROWS + (size_t)(bk - 192) * LP; }
    float bv = bias[d];
    float s = 0.f;
    for (int l = half; l < L; l += 2) {
        size_t o = (rowbase + l) * D_ + d;
        float v = x0[o] + x1[o] + bv;
        s += v * v;
    }
    red[t] = s;
    __syncthreads();
    if (t < 128) {
        float tot = red[t] + red[t + 128];
        inv[(size_t)bk * D_ + t] = 1.0f / fmaxf(sqrtf(tot), 1e-12f);
    }
}

// ---------------- scale + bf16 + scatter into fragment layouts ----------------
// qfrag: [qp(48)][mt(5)][ks(4)][lane(64)][8]   (prow = (b&1)*35 + l, pad rows 70..79 = 0)
// pfrag: [side*96+pb][nt(12)][ks(4)][lane(64)][8] (pad rows 180..191 = 0)
__global__ __launch_bounds__(256) void scatter_k(
    const float* __restrict__ x0, const float* __restrict__ x1, const float* __restrict__ bias,
    const float* __restrict__ inv,
    unsigned short* __restrict__ qfrag, unsigned short* __restrict__ pfrag) {
    int idx = blockIdx.x * 256 + threadIdx.x;            // NROWS*128 exactly
    int row = idx >> 7, d = idx & 127;
    int ks = d >> 5, quad = (d >> 3) & 3, j = d & 7;
    int bk; unsigned short* dest;
    if (row < QROWS) {
        int b = row / 35, l = row - b * 35;
        bk = b;
        int qp = b >> 1, prow = (b & 1) * 35 + l;
        int mt = prow >> 4, mm = prow & 15;
        dest = qfrag + (((size_t)((qp * 5 + mt) * 4 + ks) * 64 + quad * 16 + mm) * 8 + j);
    } else if (row < QROWS + PROWS) {
        int r2 = row - QROWS;
        int b = r2 / 180, l = r2 - b * 180;
        bk = 96 + b;
        int nt = l >> 4, mm = l & 15;
        dest = pfrag + (((size_t)((b * 12 + nt) * 4 + ks) * 64 + quad * 16 + mm) * 8 + j);
    } else {
        int r2 = row - (QROWS + PROWS);
        int b = r2 / 180, l = r2 - b * 180;
        bk = 192 + b;
        int nt = l >> 4, mm = l & 15;
        dest = pfrag + (((size_t)(((96 + b) * 12 + nt) * 4 + ks) * 64 + quad * 16 + mm) * 8 + j);
    }
    float v = (x0[idx] + x1[idx] + bias[d]) * inv[(size_t)bk * D_ + d];
    *dest = f2bf(v);
}

// ---------------- late interaction: one wave per (pb, side, qb-pair) ----------------
__global__ __launch_bounds__(256) void interact_k(
    const unsigned short* __restrict__ qfrag, const unsigned short* __restrict__ pfrag,
    const unsigned char* __restrict__ maskc, float* __restrict__ out) {
    int wave = threadIdx.x >> 6, lane = threadIdx.x & 63;
    int w = blockIdx.x * 4 + wave;                       // 9216 waves
    int pb = w / 96;
    int t = w - pb * 96;
    int side = t / 48, qp = t - side * 48;
    int m = lane & 15, quad = lane >> 4;

    const unsigned short* pbase = pfrag + (size_t)(side * 96 + pb) * 12 * 4 * 64 * 8;
    const unsigned char* mk = maskc + (size_t)(side * 96 + pb) * LP;

    // A frags: 5 m-tiles x 4 ks, lane-contiguous
    s16x8 a[5][4];
    const unsigned short* qbase = qfrag + (size_t)qp * 5 * 4 * 64 * 8;
#pragma unroll
    for (int mt = 0; mt < 5; mt++)
#pragma unroll
        for (int ks = 0; ks < 4; ks++)
            a[mt][ks] = *(const s16x8*)(qbase + ((size_t)(mt * 4 + ks) * 64 + lane) * 8);

    float rmax[5][4];
#pragma unroll
    for (int mt = 0; mt < 5; mt++)
#pragma unroll
        for (int r = 0; r < 4; r++) rmax[mt][r] = NEGF;

    for (int nt = 0; nt < 12; nt++) {
        int l = nt * 16 + m;
        int lc = l < LP ? l : LP - 1;
        bool valid = (l < LP) && (mk[lc] != 0);
        s16x8 bfr[4];
#pragma unroll
        for (int ks = 0; ks < 4; ks++)
            bfr[ks] = *(const s16x8*)(pbase + ((size_t)(nt * 4 + ks) * 64 + lane) * 8);
#pragma unroll
        for (int mt = 0; mt < 5; mt++) {
            f32x4 acc = (f32x4){0.f, 0.f, 0.f, 0.f};
#pragma unroll
            for (int ks = 0; ks < 4; ks++)
                acc = __builtin_amdgcn_mfma_f32_16x16x32_bf16(a[mt][ks], bfr[ks], acc, 0, 0, 0);
#pragma unroll
            for (int r = 0; r < 4; r++) {
                float v = valid ? acc[r] : NEGF;
                rmax[mt][r] = fmaxf(rmax[mt][r], v);
            }
        }
    }

    // max over the 16 token-columns per group
#pragma unroll
    for (int mt = 0; mt < 5; mt++)
#pragma unroll
        for (int r = 0; r < 4; r++) {
            float v = rmax[mt][r];
            v = fmaxf(v, __shfl_xor(v, 1));
            v = fmaxf(v, __shfl_xor(v, 2));
            v = fmaxf(v, __shfl_xor(v, 4));
            v = fmaxf(v, __shfl_xor(v, 8));
            rmax[mt][r] = v;
        }
    float s0 = 0.f, s1 = 0.f;
#pragma unroll
    for (int mt = 0; mt < 5; mt++)
#pragma unroll
        for (int r = 0; r < 4; r++) {
            int prow = mt * 16 + quad * 4 + r;
            float v = rmax[mt][r];
            if (prow < 35) s0 += v;
            else if (prow < 70) s1 += v;
        }
    s0 += __shfl_xor(s0, 16); s0 += __shfl_xor(s0, 32);
    s1 += __shfl_xor(s1, 16); s1 += __shfl_xor(s1, 32);
    if (lane == 0) {
        int qb0 = qp * 2, qb1 = qp * 2 + 1;
        out[(size_t)qb0 * (2 * B_) + side * B_ + pb] = s0;
        out[(size_t)qb1 * (2 * B_) + side * B_ + pb] = s1;
    }
}

// ---------------- launch ----------------
extern "C" void kernel_launch(void* const* d_in, const int* in_sizes, int n_in,
                              void* d_out, int out_size, void* d_ws, size_t ws_size,
                              hipStream_t stream) {
    const float* qh   = (const float*)d_in[0];
    const float* ph   = (const float*)d_in[1];
    const float* nh   = (const float*)d_in[2];
    const float* W    = (const float*)d_in[3];
    const float* bias = (const float*)d_in[4];
    const void* pmask = d_in[5];
    const void* nmask = d_in[6];
    float* out = (float*)d_out;
    char* ws = (char*)d_ws;

    constexpr size_t CTRL_OFF  = 0;
    constexpr size_t WTHI_OFF  = 256;                                   // 196608 B
    constexpr size_t MASKC_OFF = WTHI_OFF + 196608;                     // 34560 B
    constexpr size_t INV_OFF   = MASKC_OFF + 34560 + 128;               // align
    constexpr size_t QFRAG_OFF = INV_OFF + 288 * 128 * 4;               // 983040 B
    constexpr size_t PFRAG_OFF = QFRAG_OFF + 983040;                    // 9437184 B
    constexpr size_t X0_OFF    = PFRAG_OFF + 9437184;                   // 19415040 B
    constexpr size_t X1_OFF    = X0_OFF + (size_t)NROWS * D_ * 4;

    unsigned int* ctrl     = (unsigned int*)(ws + CTRL_OFF);
    unsigned short* wthi   = (unsigned short*)(ws + WTHI_OFF);
    unsigned char* maskc   = (unsigned char*)(ws + MASKC_OFF);
    float* inv             = (float*)(ws + INV_OFF);
    unsigned short* qfrag  = (unsigned short*)(ws + QFRAG_OFF);
    unsigned short* pfrag  = (unsigned short*)(ws + PFRAG_OFF);
    float* x0              = (float*)(ws + X0_OFF);
    float* x1              = (float*)(ws + X1_OFF);

    hipMemsetAsync(ws + CTRL_OFF, 0, 64, stream);
    hipMemsetAsync(ws + QFRAG_OFF, 0, 983040 + 9437184, stream);  // zero pad rows of frag bufs

    mask_detect<<<(B_ * LP + 255) / 256, 256, 0, stream>>>((const unsigned char*)pmask, ctrl);
    mask_canon<<<(2 * B_ * LP + 255) / 256, 256, 0, stream>>>(pmask, nmask, ctrl, maskc);
    wt_build<<<48, 256, 0, stream>>>(W, wthi);
    proj_k<<<593, 256, 0, stream>>>(qh, ph, nh, wthi, x0, x1);
    norm_inv_k<<<288, 256, 0, stream>>>(x0, x1, bias, inv);
    scatter_k<<<(NROWS * D_) / 256, 256, 0, stream>>>(x0, x1, bias, inv, qfrag, pfrag);
    interact_k<<<(2 * 48 * 96) / 4, 256, 0, stream>>>(qfrag, pfrag, maskc, out);
}